// Round 7
// baseline (334.246 us; speedup 1.0000x reference)
//
#include <hip/hip_runtime.h>
#include <hip/hip_bf16.h>

#define E_EDGES   1000000
#define TILE_E    32
#define N_TILES   (E_EDGES / TILE_E)   // 31250
#define IN_DIM_K  128
#define HID_N     256
#define BN_EPS_F  1e-5f
#define MAIN_GRID 512
#define P2_GRID   512

typedef __attribute__((ext_vector_type(4))) float f32x4;
typedef __attribute__((ext_vector_type(8))) short bf16x8;

__device__ __forceinline__ unsigned short f2bf(float f) {
    __hip_bfloat16 h = __float2bfloat16(f);
    return *reinterpret_cast<unsigned short*>(&h);
}
__device__ __forceinline__ unsigned pack2(float lo, float hi) {
    return (unsigned)f2bf(lo) | ((unsigned)f2bf(hi) << 16);
}

union FragU { uint4 u; bf16x8 v; unsigned w[4]; };

__global__ void zero_stats_kernel(float* g) {
    g[threadIdx.x] = 0.0f;   // 512 threads
}

__global__ void finalize_stats_kernel(const float* __restrict__ gstat,
                                      const float* __restrict__ gamma,
                                      const float* __restrict__ beta,
                                      float* __restrict__ nAB) {
    int c = threadIdx.x;     // 256 threads
    float inv_e = 1.0f / (float)E_EDGES;
    float mean = gstat[c] * inv_e;
    float var  = fmaxf(gstat[256 + c] * inv_e - mean * mean, 0.0f);
    float a = gamma[c] * rsqrtf(var + BN_EPS_F);
    nAB[c] = a;
    nAB[256 + c] = beta[c] - mean * a;
}

// 256 threads = 4 waves (1m x 4n). Tile: 32 edges x 256 ch. 2 blocks/CU.
// Gather+pack+MFMA(stats or y). WRITE_D: also stream packed bf16 d-rows
// to ws (exact pass-2 fragment layout: row*64u + part*8u).
template <bool STATS, bool WRITE_D>
__global__ __launch_bounds__(256, 2)
void hadamard_mlp_kernel(const float* __restrict__ nodes,
                         const int* __restrict__ eidx,
                         const float* __restrict__ W1,
                         const float* __restrict__ W2,
                         const float* __restrict__ b2p,
                         float* __restrict__ gstat,
                         const float* __restrict__ nAB,
                         unsigned* __restrict__ dbuf,
                         float* __restrict__ y)
{
    __shared__ unsigned sh_d[2][TILE_E * 68];   // 32 rows x 136 bf16, dbuf
    __shared__ float s_red[2][128];             // 4 wn-waves x 32 edges, dbuf

    const int tid  = threadIdx.x;
    const int lane = tid & 63;
    const int wn   = tid >> 6;        // 0..3 (N split)
    const int l15  = lane & 15;
    const int l4   = lane >> 4;

    // ---- B fragments from W1 (f32 [128][256] row-major) ----
    bf16x8 bfrag[4][4];
    #pragma unroll
    for (int nt = 0; nt < 4; ++nt) {
        const int c = wn * 64 + nt * 16 + l15;
        #pragma unroll
        for (int kk = 0; kk < 4; ++kk) {
            const int kb = kk * 32 + 8 * l4;
            FragU t;
            #pragma unroll
            for (int j = 0; j < 4; ++j) {
                float w0 = W1[(kb + 2 * j    ) * HID_N + c];
                float w1 = W1[(kb + 2 * j + 1) * HID_N + c];
                t.w[j] = pack2(w0, w1);
            }
            bfrag[nt][kk] = t.v;
        }
    }

    float a_n[4], b_n[4], w2_n[4];
    if (!STATS) {
        #pragma unroll
        for (int nt = 0; nt < 4; ++nt) {
            const int c = wn * 64 + nt * 16 + l15;
            a_n[nt]  = nAB[c];
            b_n[nt]  = nAB[256 + c];
            w2_n[nt] = W2[c];
        }
    }
    const float b2v = b2p[0];

    float s1[4] = {0.f, 0.f, 0.f, 0.f};
    float s2[4] = {0.f, 0.f, 0.f, 0.f};

    const int ge   = tid >> 3;   // local edge 0..31
    const int part = tid & 7;    // 16-float chunk of the 128-dim row

    // ---- software pipeline state: 2 gather sets + 2 idx sets ----
    float4 gA[8], gB[8];
    int siA, diA, siB, diB;

    const int t0 = blockIdx.x;
    {   // gather tile t0 into gA
        const int e0 = t0 * TILE_E + ge;
        const int s = eidx[e0];
        const int d = eidx[E_EDGES + e0];
        const float4* ps = reinterpret_cast<const float4*>(nodes + (size_t)s * IN_DIM_K) + part * 4;
        const float4* pd = reinterpret_cast<const float4*>(nodes + (size_t)d * IN_DIM_K) + part * 4;
        #pragma unroll
        for (int j = 0; j < 4; ++j) { gA[j] = ps[j]; gA[4 + j] = pd[j]; }
    }
    if (t0 + MAIN_GRID < N_TILES) {   // gather tile t0+G into gB
        const int e1 = (t0 + MAIN_GRID) * TILE_E + ge;
        const int s = eidx[e1];
        const int d = eidx[E_EDGES + e1];
        const float4* ps = reinterpret_cast<const float4*>(nodes + (size_t)s * IN_DIM_K) + part * 4;
        const float4* pd = reinterpret_cast<const float4*>(nodes + (size_t)d * IN_DIM_K) + part * 4;
        #pragma unroll
        for (int j = 0; j < 4; ++j) { gB[j] = ps[j]; gB[4 + j] = pd[j]; }
    }
    siA = diA = siB = diB = 0;
    if (t0 + 2 * MAIN_GRID < N_TILES) {
        const int e = (t0 + 2 * MAIN_GRID) * TILE_E + ge;
        siA = eidx[e];  diA = eidx[E_EDGES + e];
    }
    if (t0 + 3 * MAIN_GRID < N_TILES) {
        const int e = (t0 + 3 * MAIN_GRID) * TILE_E + ge;
        siB = eidx[e];  diB = eidx[E_EDGES + e];
    }

    int cur = 0;
    int ptile = -1;   // tile whose y-partials sit in s_red[cur^1]

#define PIPE_BODY(TILE, GV, SIV, DIV)                                          \
    {                                                                          \
        const int tile_ = (TILE);                                              \
        {   /* pack + write staged gather into sh_d[cur] (+ dbuf) */           \
            unsigned buf[8];                                                   \
            _Pragma("unroll")                                                  \
            for (int j = 0; j < 4; ++j) {                                      \
                buf[2*j]   = pack2(GV[j].x * GV[4+j].x, GV[j].y * GV[4+j].y);  \
                buf[2*j+1] = pack2(GV[j].z * GV[4+j].z, GV[j].w * GV[4+j].w);  \
            }                                                                  \
            unsigned* dst = sh_d[cur] + ge * 68 + part * 8;                    \
            *reinterpret_cast<uint4*>(dst)     = *reinterpret_cast<const uint4*>(buf);     \
            *reinterpret_cast<uint4*>(dst + 4) = *reinterpret_cast<const uint4*>(buf + 4); \
            if (WRITE_D) {                                                     \
                unsigned* dw = dbuf + (size_t)(tile_ * TILE_E + ge) * 64 + part * 8;       \
                *reinterpret_cast<uint4*>(dw)     = *reinterpret_cast<const uint4*>(buf);     \
                *reinterpret_cast<uint4*>(dw + 4) = *reinterpret_cast<const uint4*>(buf + 4); \
            }                                                                  \
        }                                                                      \
        /* issue gather for tile_+2G into GV (consumed 2 bodies later) */      \
        if (tile_ + 2 * MAIN_GRID < N_TILES) {                                 \
            const float4* ps = reinterpret_cast<const float4*>(nodes + (size_t)SIV * IN_DIM_K) + part * 4; \
            const float4* pd = reinterpret_cast<const float4*>(nodes + (size_t)DIV * IN_DIM_K) + part * 4; \
            _Pragma("unroll")                                                  \
            for (int j = 0; j < 4; ++j) { GV[j] = ps[j]; GV[4+j] = pd[j]; }    \
        }                                                                      \
        /* refill idx for tile_+4G (used 2 bodies later) */                    \
        if (tile_ + 4 * MAIN_GRID < N_TILES) {                                 \
            const int e_ = (tile_ + 4 * MAIN_GRID) * TILE_E + ge;              \
            SIV = eidx[e_];  DIV = eidx[E_EDGES + e_];                         \
        }                                                                      \
        __syncthreads();                                                       \
        /* delayed y epilogue for previous tile */                             \
        if (!STATS && ptile >= 0 && tid < TILE_E) {                            \
            const float* r = s_red[cur ^ 1];                                   \
            y[ptile * TILE_E + tid] = r[tid] + r[32 + tid] + r[64 + tid]       \
                                    + r[96 + tid] + b2v;                       \
        }                                                                      \
        /* MFMA: this wave: 32 edges x 64 channels */                          \
        f32x4 acc[2][4] = {};                                                  \
        __builtin_amdgcn_s_setprio(1);                                         \
        _Pragma("unroll")                                                      \
        for (int kk = 0; kk < 4; ++kk) {                                       \
            bf16x8 af[2];                                                      \
            _Pragma("unroll")                                                  \
            for (int mt = 0; mt < 2; ++mt) {                                   \
                const int row = mt * 16 + l15;                                 \
                FragU t;                                                       \
                t.u = *reinterpret_cast<const uint4*>(sh_d[cur] + row * 68 + kk * 16 + 4 * l4); \
                af[mt] = t.v;                                                  \
            }                                                                  \
            _Pragma("unroll")                                                  \
            for (int mt = 0; mt < 2; ++mt)                                     \
                _Pragma("unroll")                                              \
                for (int nt = 0; nt < 4; ++nt)                                 \
                    acc[mt][nt] = __builtin_amdgcn_mfma_f32_16x16x32_bf16(     \
                        af[mt], bfrag[nt][kk], acc[mt][nt], 0, 0, 0);          \
        }                                                                      \
        __builtin_amdgcn_s_setprio(0);                                         \
        if (STATS) {                                                           \
            _Pragma("unroll")                                                  \
            for (int nt = 0; nt < 4; ++nt) {                                   \
                float t1s = 0.f, t2s = 0.f;                                    \
                _Pragma("unroll")                                              \
                for (int mt = 0; mt < 2; ++mt)                                 \
                    _Pragma("unroll")                                          \
                    for (int r = 0; r < 4; ++r) {                              \
                        float v = acc[mt][nt][r];                              \
                        t1s += v;                                              \
                        t2s += v * v;                                          \
                    }                                                          \
                s1[nt] += t1s;                                                 \
                s2[nt] += t2s;                                                 \
            }                                                                  \
        } else {                                                               \
            float pw[2][4];                                                    \
            _Pragma("unroll")                                                  \
            for (int mt = 0; mt < 2; ++mt)                                     \
                _Pragma("unroll")                                              \
                for (int r = 0; r < 4; ++r) {                                  \
                    float acc_y = 0.f;                                         \
                    _Pragma("unroll")                                          \
                    for (int nt = 0; nt < 4; ++nt) {                           \
                        float z = acc[mt][nt][r] * a_n[nt] + b_n[nt];          \
                        z = fmaxf(z, 0.f);                                     \
                        acc_y += z * w2_n[nt];                                 \
                    }                                                          \
                    pw[mt][r] = acc_y;                                         \
                }                                                              \
            _Pragma("unroll")                                                  \
            for (int off = 1; off < 16; off <<= 1)                             \
                _Pragma("unroll")                                              \
                for (int mt = 0; mt < 2; ++mt)                                 \
                    _Pragma("unroll")                                          \
                    for (int r = 0; r < 4; ++r)                                \
                        pw[mt][r] += __shfl_xor(pw[mt][r], off, 64);           \
            if (l15 == 0) {                                                    \
                _Pragma("unroll")                                              \
                for (int mt = 0; mt < 2; ++mt)                                 \
                    _Pragma("unroll")                                          \
                    for (int r = 0; r < 4; ++r) {                              \
                        const int el = mt * 16 + l4 * 4 + r;                   \
                        s_red[cur][wn * 32 + el] = pw[mt][r];                  \
                    }                                                          \
            }                                                                  \
            ptile = tile_;                                                     \
        }                                                                      \
        cur ^= 1;                                                              \
    }

    for (int tile = t0; tile < N_TILES; tile += 2 * MAIN_GRID) {
        PIPE_BODY(tile, gA, siA, diA);
        const int tb = tile + MAIN_GRID;
        if (tb < N_TILES) {
            PIPE_BODY(tb, gB, siB, diB);
        }
    }
#undef PIPE_BODY

    if (STATS) {
        #pragma unroll
        for (int nt = 0; nt < 4; ++nt) {
            s1[nt] += __shfl_xor(s1[nt], 16, 64);
            s1[nt] += __shfl_xor(s1[nt], 32, 64);
            s2[nt] += __shfl_xor(s2[nt], 16, 64);
            s2[nt] += __shfl_xor(s2[nt], 32, 64);
        }
        if (l4 == 0) {
            #pragma unroll
            for (int nt = 0; nt < 4; ++nt) {
                const int c = wn * 64 + nt * 16 + l15;
                atomicAdd(&gstat[c],       s1[nt]);
                atomicAdd(&gstat[256 + c], s2[nt]);
            }
        }
    } else {
        // drain the last pending y tile
        __syncthreads();
        if (ptile >= 0 && tid < TILE_E) {
            const float* r = s_red[cur ^ 1];
            y[ptile * TILE_E + tid] = r[tid] + r[32 + tid] + r[64 + tid]
                                    + r[96 + tid] + b2v;
        }
    }
}

// Pass 2 fast path: d already in ws in fragment layout — pure sequential
// stream, no gather, no pack, no A-staging LDS. Depth-1 prefetch (fA/fB).
__global__ __launch_bounds__(256, 2)
void pass2_stream_kernel(const unsigned* __restrict__ dbuf,
                         const float* __restrict__ W1,
                         const float* __restrict__ W2,
                         const float* __restrict__ b2p,
                         const float* __restrict__ nAB,
                         float* __restrict__ y)
{
    __shared__ float s_red[2][128];

    const int tid  = threadIdx.x;
    const int lane = tid & 63;
    const int wn   = tid >> 6;
    const int l15  = lane & 15;
    const int l4   = lane >> 4;

    bf16x8 bfrag[4][4];
    #pragma unroll
    for (int nt = 0; nt < 4; ++nt) {
        const int c = wn * 64 + nt * 16 + l15;
        #pragma unroll
        for (int kk = 0; kk < 4; ++kk) {
            const int kb = kk * 32 + 8 * l4;
            FragU t;
            #pragma unroll
            for (int j = 0; j < 4; ++j) {
                float w0 = W1[(kb + 2 * j    ) * HID_N + c];
                float w1 = W1[(kb + 2 * j + 1) * HID_N + c];
                t.w[j] = pack2(w0, w1);
            }
            bfrag[nt][kk] = t.v;
        }
    }

    float a_n[4], b_n[4], w2_n[4];
    #pragma unroll
    for (int nt = 0; nt < 4; ++nt) {
        const int c = wn * 64 + nt * 16 + l15;
        a_n[nt]  = nAB[c];
        b_n[nt]  = nAB[256 + c];
        w2_n[nt] = W2[c];
    }
    const float b2v = b2p[0];

    // lane's A-fragment address within a tile: row=(mt*16+l15), elem_u = kk*16 + l4*4
    const unsigned lbase = (unsigned)l15 * 64 + (unsigned)l4 * 4;

    uint4 fA[8], fB[8];
#define LOADF(F, TILE_)                                                        \
    {   const unsigned* p = dbuf + (size_t)(TILE_) * 2048 + lbase;             \
        _Pragma("unroll")                                                      \
        for (int mt = 0; mt < 2; ++mt)                                         \
            _Pragma("unroll")                                                  \
            for (int kk = 0; kk < 4; ++kk)                                     \
                F[mt * 4 + kk] = *reinterpret_cast<const uint4*>(p + mt * 1024 + kk * 16); \
    }

    const int t0 = blockIdx.x;
    LOADF(fA, t0);

    int cur = 0;
    int ptile = -1;

#define P2_BODY(TILE, FC, FN)                                                  \
    {                                                                          \
        const int tile_ = (TILE);                                              \
        const int ntile_ = tile_ + P2_GRID;                                    \
        if (ntile_ < N_TILES) LOADF(FN, ntile_);                               \
        __syncthreads();                                                       \
        if (ptile >= 0 && tid < TILE_E) {                                      \
            const float* r = s_red[cur ^ 1];                                   \
            y[ptile * TILE_E + tid] = r[tid] + r[32 + tid] + r[64 + tid]       \
                                    + r[96 + tid] + b2v;                       \
        }                                                                      \
        f32x4 acc[2][4] = {};                                                  \
        __builtin_amdgcn_s_setprio(1);                                         \
        _Pragma("unroll")                                                      \
        for (int kk = 0; kk < 4; ++kk) {                                       \
            _Pragma("unroll")                                                  \
            for (int mt = 0; mt < 2; ++mt) {                                   \
                FragU t;                                                       \
                t.u = FC[mt * 4 + kk];                                         \
                _Pragma("unroll")                                              \
                for (int nt = 0; nt < 4; ++nt)                                 \
                    acc[mt][nt] = __builtin_amdgcn_mfma_f32_16x16x32_bf16(     \
                        t.v, bfrag[nt][kk], acc[mt][nt], 0, 0, 0);             \
            }                                                                  \
        }                                                                      \
        __builtin_amdgcn_s_setprio(0);                                         \
        float pw[2][4];                                                        \
        _Pragma("unroll")                                                      \
        for (int mt = 0; mt < 2; ++mt)                                         \
            _Pragma("unroll")                                                  \
            for (int r = 0; r < 4; ++r) {                                      \
                float acc_y = 0.f;                                             \
                _Pragma("unroll")                                              \
                for (int nt = 0; nt < 4; ++nt) {                               \
                    float z = acc[mt][nt][r] * a_n[nt] + b_n[nt];              \
                    z = fmaxf(z, 0.f);                                         \
                    acc_y += z * w2_n[nt];                                     \
                }                                                              \
                pw[mt][r] = acc_y;                                             \
            }                                                                  \
        _Pragma("unroll")                                                      \
        for (int off = 1; off < 16; off <<= 1)                                 \
            _Pragma("unroll")                                                  \
            for (int mt = 0; mt < 2; ++mt)                                     \
                _Pragma("unroll")                                              \
                for (int r = 0; r < 4; ++r)                                    \
                    pw[mt][r] += __shfl_xor(pw[mt][r], off, 64);               \
        if (l15 == 0) {                                                        \
            _Pragma("unroll")                                                  \
            for (int mt = 0; mt < 2; ++mt)                                     \
                _Pragma("unroll")                                              \
                for (int r = 0; r < 4; ++r) {                                  \
                    const int el = mt * 16 + l4 * 4 + r;                       \
                    s_red[cur][wn * 32 + el] = pw[mt][r];                      \
                }                                                              \
        }                                                                      \
        ptile = tile_;                                                         \
        cur ^= 1;                                                              \
    }

    for (int tile = t0; tile < N_TILES; tile += 2 * P2_GRID) {
        P2_BODY(tile, fA, fB);
        const int tb = tile + P2_GRID;
        if (tb < N_TILES) {
            P2_BODY(tb, fB, fA);
        }
    }
#undef P2_BODY
#undef LOADF

    __syncthreads();
    if (ptile >= 0 && tid < TILE_E) {
        const float* r = s_red[cur ^ 1];
        y[ptile * TILE_E + tid] = r[tid] + r[32 + tid] + r[64 + tid]
                                + r[96 + tid] + b2v;
    }
}

extern "C" void kernel_launch(void* const* d_in, const int* in_sizes, int n_in,
                              void* d_out, int out_size, void* d_ws, size_t ws_size,
                              hipStream_t stream) {
    const float* nodes = (const float*)d_in[0];
    const int*   eidx  = (const int*)d_in[1];
    const float* W1    = (const float*)d_in[2];
    // d_in[3] = b1 : analytically cancelled by batch-norm, unused
    const float* gamma = (const float*)d_in[4];
    const float* beta  = (const float*)d_in[5];
    const float* W2    = (const float*)d_in[6];
    const float* b2    = (const float*)d_in[7];

    float* ws    = (float*)d_ws;
    float* gstat = ws;          // 512 f32: sum_h[256], sumsq_h[256]
    float* nAB   = ws + 512;    // 512 f32: A[256], B[256]
    unsigned* dbuf = (unsigned*)((char*)d_ws + 4096);   // 256 MB packed d
    float* y     = (float*)d_out;

    const size_t D_BYTES = (size_t)E_EDGES * IN_DIM_K * 2;   // 256 MB
    const bool fast = ws_size >= (4096 + D_BYTES);

    zero_stats_kernel<<<1, 512, 0, stream>>>(gstat);
    if (fast) {
        hadamard_mlp_kernel<true, true><<<MAIN_GRID, 256, 0, stream>>>(
            nodes, eidx, W1, W2, b2, gstat, nAB, dbuf, y);
        finalize_stats_kernel<<<1, 256, 0, stream>>>(gstat, gamma, beta, nAB);
        pass2_stream_kernel<<<P2_GRID, 256, 0, stream>>>(
            dbuf, W1, W2, b2, nAB, y);
    } else {
        hadamard_mlp_kernel<true, false><<<MAIN_GRID, 256, 0, stream>>>(
            nodes, eidx, W1, W2, b2, gstat, nAB, dbuf, y);
        finalize_stats_kernel<<<1, 256, 0, stream>>>(gstat, gamma, beta, nAB);
        hadamard_mlp_kernel<false, false><<<MAIN_GRID, 256, 0, stream>>>(
            nodes, eidx, W1, W2, b2, gstat, nAB, dbuf, y);
    }
}

// Round 8
// 270.539 us; speedup vs baseline: 1.2355x; 1.2355x over previous
//
#include <hip/hip_runtime.h>
#include <hip/hip_bf16.h>

#define N_NODES   500000
#define E_EDGES   1000000
#define TILE_E    32
#define N_TILES   (E_EDGES / TILE_E)   // 31250
#define IN_DIM_K  128
#define HID_N     256
#define BN_EPS_F  1e-5f
#define MAIN_GRID 1024
#define CONV_GRID 2048

typedef __attribute__((ext_vector_type(4))) float f32x4;
typedef __attribute__((ext_vector_type(8))) short bf16x8;

__device__ __forceinline__ unsigned short f2bf(float f) {
    __hip_bfloat16 h = __float2bfloat16(f);
    return *reinterpret_cast<unsigned short*>(&h);
}
__device__ __forceinline__ unsigned pack2(float lo, float hi) {
    return (unsigned)f2bf(lo) | ((unsigned)f2bf(hi) << 16);
}
// product of two bf16x2 words -> bf16x2 word (f32 math, RNE pack)
__device__ __forceinline__ unsigned bfmul2(unsigned a, unsigned b) {
    float alo = __uint_as_float(a << 16);
    float ahi = __uint_as_float(a & 0xffff0000u);
    float blo = __uint_as_float(b << 16);
    float bhi = __uint_as_float(b & 0xffff0000u);
    return pack2(alo * blo, ahi * bhi);
}

union FragU { uint4 u; bf16x8 v; unsigned w[4]; };

__global__ void zero_stats_kernel(float* g) {
    g[threadIdx.x] = 0.0f;   // 512 threads
}

// nodes f32 [500000][128] -> bf16 table in ws (128 MB -> L3-resident)
__global__ void convert_nodes_kernel(const float* __restrict__ in,
                                     unsigned* __restrict__ out) {
    const size_t n4 = (size_t)N_NODES * IN_DIM_K / 8;   // uint4 outputs
    size_t i = (size_t)blockIdx.x * blockDim.x + threadIdx.x;
    const size_t stride = (size_t)gridDim.x * blockDim.x;
    for (; i < n4; i += stride) {
        float4 a = reinterpret_cast<const float4*>(in)[2 * i];
        float4 b = reinterpret_cast<const float4*>(in)[2 * i + 1];
        uint4 o;
        o.x = pack2(a.x, a.y);
        o.y = pack2(a.z, a.w);
        o.z = pack2(b.x, b.y);
        o.w = pack2(b.z, b.w);
        reinterpret_cast<uint4*>(out)[i] = o;
    }
}

__global__ void finalize_stats_kernel(const float* __restrict__ gstat,
                                      const float* __restrict__ gamma,
                                      const float* __restrict__ beta,
                                      float* __restrict__ nAB) {
    int c = threadIdx.x;     // 256 threads
    float inv_e = 1.0f / (float)E_EDGES;
    float mean = gstat[c] * inv_e;
    float var  = fmaxf(gstat[256 + c] * inv_e - mean * mean, 0.0f);
    float a = gamma[c] * rsqrtf(var + BN_EPS_F);
    nAB[c] = a;
    nAB[256 + c] = beta[c] - mean * a;
}

// 256 threads = 4 waves (1m x 4n). Tile: 32 edges x 256 ch.
// BFT: gather from the bf16 node table (L3-resident, half the lines).
// Depth-2 gather pipeline (named gA/gB), LDS dbuf, ONE barrier/tile.
template <bool STATS, bool BFT>
__global__ __launch_bounds__(256, 2)
void hadamard_mlp_kernel(const float* __restrict__ nodes,
                         const unsigned* __restrict__ nbf,
                         const int* __restrict__ eidx,
                         const float* __restrict__ W1,
                         const float* __restrict__ W2,
                         const float* __restrict__ b2p,
                         float* __restrict__ gstat,
                         const float* __restrict__ nAB,
                         float* __restrict__ y)
{
    __shared__ unsigned sh_d[2][TILE_E * 68];   // 32 rows x 136 bf16, dbuf
    __shared__ float s_red[2][128];             // 4 wn-waves x 32 edges, dbuf

    const int tid  = threadIdx.x;
    const int lane = tid & 63;
    const int wn   = tid >> 6;        // 0..3 (N split)
    const int l15  = lane & 15;
    const int l4   = lane >> 4;

    // ---- B fragments from W1 (f32 [128][256] row-major) ----
    bf16x8 bfrag[4][4];
    #pragma unroll
    for (int nt = 0; nt < 4; ++nt) {
        const int c = wn * 64 + nt * 16 + l15;
        #pragma unroll
        for (int kk = 0; kk < 4; ++kk) {
            const int kb = kk * 32 + 8 * l4;
            FragU t;
            #pragma unroll
            for (int j = 0; j < 4; ++j) {
                float w0 = W1[(kb + 2 * j    ) * HID_N + c];
                float w1 = W1[(kb + 2 * j + 1) * HID_N + c];
                t.w[j] = pack2(w0, w1);
            }
            bfrag[nt][kk] = t.v;
        }
    }

    float a_n[4], b_n[4], w2_n[4];
    if (!STATS) {
        #pragma unroll
        for (int nt = 0; nt < 4; ++nt) {
            const int c = wn * 64 + nt * 16 + l15;
            a_n[nt]  = nAB[c];
            b_n[nt]  = nAB[256 + c];
            w2_n[nt] = W2[c];
        }
    }
    const float b2v = b2p[0];

    float s1[4] = {0.f, 0.f, 0.f, 0.f};
    float s2[4] = {0.f, 0.f, 0.f, 0.f};

    const int ge   = tid >> 3;   // local edge 0..31
    const int part = tid & 7;    // 16-elem chunk of the 128-dim row

    // ---- software pipeline state (named, static-indexed) ----
    uint4  gA[4], gB[4];   // bf16 path: 2 src + 2 dst uint4 (32B each)
    float4 hA[8], hB[8];   // f32 fallback path
    int siA, diA, siB, diB;

#define GATHER(GV, HV, SNODE, DNODE)                                           \
    if constexpr (BFT) {                                                       \
        const uint4* ps = reinterpret_cast<const uint4*>(nbf + (size_t)(SNODE) * 64) + part * 2; \
        const uint4* pd = reinterpret_cast<const uint4*>(nbf + (size_t)(DNODE) * 64) + part * 2; \
        GV[0] = ps[0]; GV[1] = ps[1]; GV[2] = pd[0]; GV[3] = pd[1];            \
    } else {                                                                   \
        const float4* ps = reinterpret_cast<const float4*>(nodes + (size_t)(SNODE) * IN_DIM_K) + part * 4; \
        const float4* pd = reinterpret_cast<const float4*>(nodes + (size_t)(DNODE) * IN_DIM_K) + part * 4; \
        _Pragma("unroll")                                                      \
        for (int j = 0; j < 4; ++j) { HV[j] = ps[j]; HV[4 + j] = pd[j]; }      \
    }

#define PACKBUF(GV, HV, buf)                                                   \
    if constexpr (BFT) {                                                       \
        buf[0] = bfmul2(GV[0].x, GV[2].x); buf[1] = bfmul2(GV[0].y, GV[2].y);  \
        buf[2] = bfmul2(GV[0].z, GV[2].z); buf[3] = bfmul2(GV[0].w, GV[2].w);  \
        buf[4] = bfmul2(GV[1].x, GV[3].x); buf[5] = bfmul2(GV[1].y, GV[3].y);  \
        buf[6] = bfmul2(GV[1].z, GV[3].z); buf[7] = bfmul2(GV[1].w, GV[3].w);  \
    } else {                                                                   \
        _Pragma("unroll")                                                      \
        for (int j = 0; j < 4; ++j) {                                          \
            buf[2*j]   = pack2(HV[j].x * HV[4+j].x, HV[j].y * HV[4+j].y);      \
            buf[2*j+1] = pack2(HV[j].z * HV[4+j].z, HV[j].w * HV[4+j].w);      \
        }                                                                      \
    }

    const int t0 = blockIdx.x;
    {
        const int e0 = t0 * TILE_E + ge;
        const int s = eidx[e0];
        const int d = eidx[E_EDGES + e0];
        GATHER(gA, hA, s, d);
    }
    if (t0 + MAIN_GRID < N_TILES) {
        const int e1 = (t0 + MAIN_GRID) * TILE_E + ge;
        const int s = eidx[e1];
        const int d = eidx[E_EDGES + e1];
        GATHER(gB, hB, s, d);
    }
    siA = diA = siB = diB = 0;
    if (t0 + 2 * MAIN_GRID < N_TILES) {
        const int e = (t0 + 2 * MAIN_GRID) * TILE_E + ge;
        siA = eidx[e];  diA = eidx[E_EDGES + e];
    }
    if (t0 + 3 * MAIN_GRID < N_TILES) {
        const int e = (t0 + 3 * MAIN_GRID) * TILE_E + ge;
        siB = eidx[e];  diB = eidx[E_EDGES + e];
    }

    int cur = 0;
    int ptile = -1;   // tile whose y-partials sit in s_red[cur^1]

#define PIPE_BODY(TILE, GV, HV, SIV, DIV)                                      \
    {                                                                          \
        const int tile_ = (TILE);                                              \
        {   /* pack + write staged gather into sh_d[cur] */                    \
            unsigned buf[8];                                                   \
            PACKBUF(GV, HV, buf);                                              \
            unsigned* dst = sh_d[cur] + ge * 68 + part * 8;                    \
            *reinterpret_cast<uint4*>(dst)     = *reinterpret_cast<const uint4*>(buf);     \
            *reinterpret_cast<uint4*>(dst + 4) = *reinterpret_cast<const uint4*>(buf + 4); \
        }                                                                      \
        /* issue gather for tile_+2G into GV (consumed 2 bodies later) */      \
        if (tile_ + 2 * MAIN_GRID < N_TILES) {                                 \
            GATHER(GV, HV, SIV, DIV);                                          \
        }                                                                      \
        /* refill idx for tile_+4G (used 2 bodies later) */                    \
        if (tile_ + 4 * MAIN_GRID < N_TILES) {                                 \
            const int e_ = (tile_ + 4 * MAIN_GRID) * TILE_E + ge;              \
            SIV = eidx[e_];  DIV = eidx[E_EDGES + e_];                         \
        }                                                                      \
        __syncthreads();                                                       \
        /* delayed y epilogue for previous tile */                             \
        if (!STATS && ptile >= 0 && tid < TILE_E) {                            \
            const float* r = s_red[cur ^ 1];                                   \
            y[ptile * TILE_E + tid] = r[tid] + r[32 + tid] + r[64 + tid]       \
                                    + r[96 + tid] + b2v;                       \
        }                                                                      \
        /* MFMA: this wave: 32 edges x 64 channels */                          \
        f32x4 acc[2][4] = {};                                                  \
        __builtin_amdgcn_s_setprio(1);                                         \
        _Pragma("unroll")                                                      \
        for (int kk = 0; kk < 4; ++kk) {                                       \
            bf16x8 af[2];                                                      \
            _Pragma("unroll")                                                  \
            for (int mt = 0; mt < 2; ++mt) {                                   \
                const int row = mt * 16 + l15;                                 \
                FragU t;                                                       \
                t.u = *reinterpret_cast<const uint4*>(sh_d[cur] + row * 68 + kk * 16 + 4 * l4); \
                af[mt] = t.v;                                                  \
            }                                                                  \
            _Pragma("unroll")                                                  \
            for (int mt = 0; mt < 2; ++mt)                                     \
                _Pragma("unroll")                                              \
                for (int nt = 0; nt < 4; ++nt)                                 \
                    acc[mt][nt] = __builtin_amdgcn_mfma_f32_16x16x32_bf16(     \
                        af[mt], bfrag[nt][kk], acc[mt][nt], 0, 0, 0);          \
        }                                                                      \
        __builtin_amdgcn_s_setprio(0);                                         \
        if (STATS) {                                                           \
            _Pragma("unroll")                                                  \
            for (int nt = 0; nt < 4; ++nt) {                                   \
                float t1s = 0.f, t2s = 0.f;                                    \
                _Pragma("unroll")                                              \
                for (int mt = 0; mt < 2; ++mt)                                 \
                    _Pragma("unroll")                                          \
                    for (int r = 0; r < 4; ++r) {                              \
                        float v = acc[mt][nt][r];                              \
                        t1s += v;                                              \
                        t2s += v * v;                                          \
                    }                                                          \
                s1[nt] += t1s;                                                 \
                s2[nt] += t2s;                                                 \
            }                                                                  \
        } else {                                                               \
            float pw[2][4];                                                    \
            _Pragma("unroll")                                                  \
            for (int mt = 0; mt < 2; ++mt)                                     \
                _Pragma("unroll")                                              \
                for (int r = 0; r < 4; ++r) {                                  \
                    float acc_y = 0.f;                                         \
                    _Pragma("unroll")                                          \
                    for (int nt = 0; nt < 4; ++nt) {                           \
                        float z = acc[mt][nt][r] * a_n[nt] + b_n[nt];          \
                        z = fmaxf(z, 0.f);                                     \
                        acc_y += z * w2_n[nt];                                 \
                    }                                                          \
                    pw[mt][r] = acc_y;                                         \
                }                                                              \
            _Pragma("unroll")                                                  \
            for (int off = 1; off < 16; off <<= 1)                             \
                _Pragma("unroll")                                              \
                for (int mt = 0; mt < 2; ++mt)                                 \
                    _Pragma("unroll")                                          \
                    for (int r = 0; r < 4; ++r)                                \
                        pw[mt][r] += __shfl_xor(pw[mt][r], off, 64);           \
            if (l15 == 0) {                                                    \
                _Pragma("unroll")                                              \
                for (int mt = 0; mt < 2; ++mt)                                 \
                    _Pragma("unroll")                                          \
                    for (int r = 0; r < 4; ++r) {                              \
                        const int el = mt * 16 + l4 * 4 + r;                   \
                        s_red[cur][wn * 32 + el] = pw[mt][r];                  \
                    }                                                          \
            }                                                                  \
            ptile = tile_;                                                     \
        }                                                                      \
        cur ^= 1;                                                              \
    }

    for (int tile = t0; tile < N_TILES; tile += 2 * MAIN_GRID) {
        PIPE_BODY(tile, gA, hA, siA, diA);
        const int tb = tile + MAIN_GRID;
        if (tb < N_TILES) {
            PIPE_BODY(tb, gB, hB, siB, diB);
        }
    }
#undef PIPE_BODY
#undef GATHER
#undef PACKBUF

    if (STATS) {
        #pragma unroll
        for (int nt = 0; nt < 4; ++nt) {
            s1[nt] += __shfl_xor(s1[nt], 16, 64);
            s1[nt] += __shfl_xor(s1[nt], 32, 64);
            s2[nt] += __shfl_xor(s2[nt], 16, 64);
            s2[nt] += __shfl_xor(s2[nt], 32, 64);
        }
        if (l4 == 0) {
            #pragma unroll
            for (int nt = 0; nt < 4; ++nt) {
                const int c = wn * 64 + nt * 16 + l15;
                atomicAdd(&gstat[c],       s1[nt]);
                atomicAdd(&gstat[256 + c], s2[nt]);
            }
        }
    } else {
        // drain the last pending y tile
        __syncthreads();
        if (ptile >= 0 && tid < TILE_E) {
            const float* r = s_red[cur ^ 1];
            y[ptile * TILE_E + tid] = r[tid] + r[32 + tid] + r[64 + tid]
                                    + r[96 + tid] + b2v;
        }
    }
}

extern "C" void kernel_launch(void* const* d_in, const int* in_sizes, int n_in,
                              void* d_out, int out_size, void* d_ws, size_t ws_size,
                              hipStream_t stream) {
    const float* nodes = (const float*)d_in[0];
    const int*   eidx  = (const int*)d_in[1];
    const float* W1    = (const float*)d_in[2];
    // d_in[3] = b1 : analytically cancelled by batch-norm, unused
    const float* gamma = (const float*)d_in[4];
    const float* beta  = (const float*)d_in[5];
    const float* W2    = (const float*)d_in[6];
    const float* b2    = (const float*)d_in[7];

    float* ws    = (float*)d_ws;
    float* gstat = ws;          // 512 f32: sum_h[256], sumsq_h[256]
    float* nAB   = ws + 512;    // 512 f32: A[256], B[256]
    unsigned* nbf = (unsigned*)((char*)d_ws + 4096);   // 128 MB bf16 node table
    float* y     = (float*)d_out;

    const size_t T_BYTES = (size_t)N_NODES * IN_DIM_K * 2;   // 128 MB
    const bool fast = ws_size >= (4096 + T_BYTES);

    zero_stats_kernel<<<1, 512, 0, stream>>>(gstat);
    if (fast) {
        convert_nodes_kernel<<<CONV_GRID, 256, 0, stream>>>(nodes, nbf);
        hadamard_mlp_kernel<true, true><<<MAIN_GRID, 256, 0, stream>>>(
            nodes, nbf, eidx, W1, W2, b2, gstat, nAB, y);
        finalize_stats_kernel<<<1, 256, 0, stream>>>(gstat, gamma, beta, nAB);
        hadamard_mlp_kernel<false, true><<<MAIN_GRID, 256, 0, stream>>>(
            nodes, nbf, eidx, W1, W2, b2, gstat, nAB, y);
    } else {
        hadamard_mlp_kernel<true, false><<<MAIN_GRID, 256, 0, stream>>>(
            nodes, nbf, eidx, W1, W2, b2, gstat, nAB, y);
        finalize_stats_kernel<<<1, 256, 0, stream>>>(gstat, gamma, beta, nAB);
        hadamard_mlp_kernel<false, false><<<MAIN_GRID, 256, 0, stream>>>(
            nodes, nbf, eidx, W1, W2, b2, gstat, nAB, y);
    }
}

// Round 10
// 259.072 us; speedup vs baseline: 1.2902x; 1.0443x over previous
//
#include <hip/hip_runtime.h>
#include <hip/hip_bf16.h>

#define N_NODES   500000
#define E_EDGES   1000000
#define TILE_E    32
#define N_TILES   (E_EDGES / TILE_E)   // 31250
#define IN_DIM_K  128
#define HID_N     256
#define BN_EPS_F  1e-5f
#define MAIN_GRID 768                  // 3 blocks/CU x 256 CU
#define CONV_GRID 2048

typedef __attribute__((ext_vector_type(4))) float f32x4;
typedef __attribute__((ext_vector_type(8))) short bf16x8;

__device__ __forceinline__ unsigned short f2bf(float f) {
    __hip_bfloat16 h = __float2bfloat16(f);
    return *reinterpret_cast<unsigned short*>(&h);
}
__device__ __forceinline__ unsigned pack2(float lo, float hi) {
    return (unsigned)f2bf(lo) | ((unsigned)f2bf(hi) << 16);
}
// product of two bf16x2 words -> bf16x2 word (f32 math, RNE pack)
__device__ __forceinline__ unsigned bfmul2(unsigned a, unsigned b) {
    float alo = __uint_as_float(a << 16);
    float ahi = __uint_as_float(a & 0xffff0000u);
    float blo = __uint_as_float(b << 16);
    float bhi = __uint_as_float(b & 0xffff0000u);
    return pack2(alo * blo, ahi * bhi);
}

union FragU { uint4 u; bf16x8 v; unsigned w[4]; };

__global__ void zero_stats_kernel(float* g) {
    g[threadIdx.x] = 0.0f;   // 512 threads (fallback path only)
}

// nodes f32 [500000][128] -> bf16 table in ws (128 MB -> L3-resident).
// Block 0 also zeroes gstat: 256 threads x 2 entries = all 512 floats
// (round-9 bug: `tid<512` with 256-thread blocks left gstat[256..511]
// holding the 0xAA poison -> nondeterministic output -> tripwire).
__global__ void convert_nodes_kernel(const float* __restrict__ in,
                                     unsigned* __restrict__ out,
                                     float* __restrict__ gstat) {
    if (blockIdx.x == 0) {
        gstat[threadIdx.x] = 0.0f;
        gstat[256 + threadIdx.x] = 0.0f;
    }
    const size_t n4 = (size_t)N_NODES * IN_DIM_K / 8;   // uint4 outputs
    size_t i = (size_t)blockIdx.x * blockDim.x + threadIdx.x;
    const size_t stride = (size_t)gridDim.x * blockDim.x;
    for (; i < n4; i += stride) {
        float4 a = reinterpret_cast<const float4*>(in)[2 * i];
        float4 b = reinterpret_cast<const float4*>(in)[2 * i + 1];
        uint4 o;
        o.x = pack2(a.x, a.y);
        o.y = pack2(a.z, a.w);
        o.z = pack2(b.x, b.y);
        o.w = pack2(b.z, b.w);
        reinterpret_cast<uint4*>(out)[i] = o;
    }
}

// 256 threads = 4 waves (1m x 4n). Tile: 32 edges x 256 ch.
// BFT: gather from the bf16 node table (L3-resident, half the lines).
// Depth-1 gather pipeline, LDS dbuf, ONE barrier/tile, 3 blocks/CU.
// Pass 2 computes BN scale/shift from gstat directly (no finalize kernel).
template <bool STATS, bool BFT>
__global__ __launch_bounds__(256, 3)
void hadamard_mlp_kernel(const float* __restrict__ nodes,
                         const unsigned* __restrict__ nbf,
                         const int* __restrict__ eidx,
                         const float* __restrict__ W1,
                         const float* __restrict__ W2,
                         const float* __restrict__ b2p,
                         float* __restrict__ gstat,
                         const float* __restrict__ gamma,
                         const float* __restrict__ beta,
                         float* __restrict__ y)
{
    __shared__ unsigned sh_d[2][TILE_E * 68];   // 32 rows x 136 bf16, dbuf
    __shared__ float s_red[2][128];             // 4 wn-waves x 32 edges, dbuf

    const int tid  = threadIdx.x;
    const int lane = tid & 63;
    const int wn   = tid >> 6;        // 0..3 (N split)
    const int l15  = lane & 15;
    const int l4   = lane >> 4;

    // ---- B fragments from W1 (f32 [128][256] row-major) ----
    bf16x8 bfrag[4][4];
    #pragma unroll
    for (int nt = 0; nt < 4; ++nt) {
        const int c = wn * 64 + nt * 16 + l15;
        #pragma unroll
        for (int kk = 0; kk < 4; ++kk) {
            const int kb = kk * 32 + 8 * l4;
            FragU t;
            #pragma unroll
            for (int j = 0; j < 4; ++j) {
                float w0 = W1[(kb + 2 * j    ) * HID_N + c];
                float w1 = W1[(kb + 2 * j + 1) * HID_N + c];
                t.w[j] = pack2(w0, w1);
            }
            bfrag[nt][kk] = t.v;
        }
    }

    float a_n[4], b_n[4], w2_n[4];
    if (!STATS) {
        const float inv_e = 1.0f / (float)E_EDGES;
        #pragma unroll
        for (int nt = 0; nt < 4; ++nt) {
            const int c = wn * 64 + nt * 16 + l15;
            float s  = gstat[c];
            float ss = gstat[256 + c];
            float mean = s * inv_e;
            float var  = fmaxf(ss * inv_e - mean * mean, 0.0f);
            float a = gamma[c] * rsqrtf(var + BN_EPS_F);
            a_n[nt]  = a;
            b_n[nt]  = beta[c] - mean * a;
            w2_n[nt] = W2[c];
        }
    }
    const float b2v = b2p[0];

    float s1[4] = {0.f, 0.f, 0.f, 0.f};
    float s2[4] = {0.f, 0.f, 0.f, 0.f};

    const int ge   = tid >> 3;   // local edge 0..31
    const int part = tid & 7;    // 16-elem chunk of the 128-dim row

    // ---- depth-1 pipeline state ----
    uint4  g[4];    // bf16 path: 2 src + 2 dst uint4 (32B each)
    float4 h[8];    // f32 fallback path
    int si, di;     // indices one tile ahead

#define GATHER(SNODE, DNODE)                                                   \
    if constexpr (BFT) {                                                       \
        const uint4* ps = reinterpret_cast<const uint4*>(nbf + (size_t)(SNODE) * 64) + part * 2; \
        const uint4* pd = reinterpret_cast<const uint4*>(nbf + (size_t)(DNODE) * 64) + part * 2; \
        g[0] = ps[0]; g[1] = ps[1]; g[2] = pd[0]; g[3] = pd[1];                \
    } else {                                                                   \
        const float4* ps = reinterpret_cast<const float4*>(nodes + (size_t)(SNODE) * IN_DIM_K) + part * 4; \
        const float4* pd = reinterpret_cast<const float4*>(nodes + (size_t)(DNODE) * IN_DIM_K) + part * 4; \
        _Pragma("unroll")                                                      \
        for (int j = 0; j < 4; ++j) { h[j] = ps[j]; h[4 + j] = pd[j]; }        \
    }

    const int t0 = blockIdx.x;
    {
        const int e0 = t0 * TILE_E + ge;
        const int s = eidx[e0];
        const int d = eidx[E_EDGES + e0];
        GATHER(s, d);
    }
    si = di = 0;
    if (t0 + MAIN_GRID < N_TILES) {
        const int e = (t0 + MAIN_GRID) * TILE_E + ge;
        si = eidx[e];  di = eidx[E_EDGES + e];
    }

    int cur = 0;
    int ptile = -1;   // tile whose y-partials sit in s_red[cur^1]

    for (int tile = t0; tile < N_TILES; tile += MAIN_GRID) {
        // ---- pack + write staged gather into sh_d[cur] ----
        {
            unsigned buf[8];
            if constexpr (BFT) {
                buf[0] = bfmul2(g[0].x, g[2].x); buf[1] = bfmul2(g[0].y, g[2].y);
                buf[2] = bfmul2(g[0].z, g[2].z); buf[3] = bfmul2(g[0].w, g[2].w);
                buf[4] = bfmul2(g[1].x, g[3].x); buf[5] = bfmul2(g[1].y, g[3].y);
                buf[6] = bfmul2(g[1].z, g[3].z); buf[7] = bfmul2(g[1].w, g[3].w);
            } else {
                #pragma unroll
                for (int j = 0; j < 4; ++j) {
                    buf[2*j]   = pack2(h[j].x * h[4+j].x, h[j].y * h[4+j].y);
                    buf[2*j+1] = pack2(h[j].z * h[4+j].z, h[j].w * h[4+j].w);
                }
            }
            unsigned* dst = sh_d[cur] + ge * 68 + part * 8;
            *reinterpret_cast<uint4*>(dst)     = *reinterpret_cast<const uint4*>(buf);
            *reinterpret_cast<uint4*>(dst + 4) = *reinterpret_cast<const uint4*>(buf + 4);
        }
        // ---- issue gather for next tile (in flight during MFMA) ----
        if (tile + MAIN_GRID < N_TILES) {
            GATHER(si, di);
        }
        // ---- prefetch indices two tiles ahead ----
        if (tile + 2 * MAIN_GRID < N_TILES) {
            const int e = (tile + 2 * MAIN_GRID) * TILE_E + ge;
            si = eidx[e];  di = eidx[E_EDGES + e];
        }

        __syncthreads();   // sh_d[cur] visible; s_red[cur^1] complete

        // ---- delayed y epilogue for previous tile ----
        if (!STATS && ptile >= 0 && tid < TILE_E) {
            const float* r = s_red[cur ^ 1];
            y[ptile * TILE_E + tid] = r[tid] + r[32 + tid] + r[64 + tid]
                                    + r[96 + tid] + b2v;
        }

        // ---- MFMA: this wave: 32 edges x 64 channels ----
        f32x4 acc[2][4] = {};
        __builtin_amdgcn_s_setprio(1);
        #pragma unroll
        for (int kk = 0; kk < 4; ++kk) {
            bf16x8 af[2];
            #pragma unroll
            for (int mt = 0; mt < 2; ++mt) {
                const int row = mt * 16 + l15;
                FragU t;
                t.u = *reinterpret_cast<const uint4*>(sh_d[cur] + row * 68 + kk * 16 + 4 * l4);
                af[mt] = t.v;
            }
            #pragma unroll
            for (int mt = 0; mt < 2; ++mt)
                #pragma unroll
                for (int nt = 0; nt < 4; ++nt)
                    acc[mt][nt] = __builtin_amdgcn_mfma_f32_16x16x32_bf16(
                        af[mt], bfrag[nt][kk], acc[mt][nt], 0, 0, 0);
        }
        __builtin_amdgcn_s_setprio(0);

        if (STATS) {
            #pragma unroll
            for (int nt = 0; nt < 4; ++nt) {
                float t1s = 0.f, t2s = 0.f;
                #pragma unroll
                for (int mt = 0; mt < 2; ++mt)
                    #pragma unroll
                    for (int r = 0; r < 4; ++r) {
                        float v = acc[mt][nt][r];
                        t1s += v;
                        t2s += v * v;
                    }
                s1[nt] += t1s;
                s2[nt] += t2s;
            }
        } else {
            float pw[2][4];
            #pragma unroll
            for (int mt = 0; mt < 2; ++mt)
                #pragma unroll
                for (int r = 0; r < 4; ++r) {
                    float acc_y = 0.f;
                    #pragma unroll
                    for (int nt = 0; nt < 4; ++nt) {
                        float z = acc[mt][nt][r] * a_n[nt] + b_n[nt];
                        z = fmaxf(z, 0.f);
                        acc_y += z * w2_n[nt];
                    }
                    pw[mt][r] = acc_y;
                }
            #pragma unroll
            for (int off = 1; off < 16; off <<= 1)
                #pragma unroll
                for (int mt = 0; mt < 2; ++mt)
                    #pragma unroll
                    for (int r = 0; r < 4; ++r)
                        pw[mt][r] += __shfl_xor(pw[mt][r], off, 64);
            if (l15 == 0) {
                #pragma unroll
                for (int mt = 0; mt < 2; ++mt)
                    #pragma unroll
                    for (int r = 0; r < 4; ++r) {
                        const int el = mt * 16 + l4 * 4 + r;
                        s_red[cur][wn * 32 + el] = pw[mt][r];
                    }
            }
            ptile = tile;
        }
        cur ^= 1;
    }
#undef GATHER

    if (STATS) {
        #pragma unroll
        for (int nt = 0; nt < 4; ++nt) {
            s1[nt] += __shfl_xor(s1[nt], 16, 64);
            s1[nt] += __shfl_xor(s1[nt], 32, 64);
            s2[nt] += __shfl_xor(s2[nt], 16, 64);
            s2[nt] += __shfl_xor(s2[nt], 32, 64);
        }
        if (l4 == 0) {
            #pragma unroll
            for (int nt = 0; nt < 4; ++nt) {
                const int c = wn * 64 + nt * 16 + l15;
                atomicAdd(&gstat[c],       s1[nt]);
                atomicAdd(&gstat[256 + c], s2[nt]);
            }
        }
    } else {
        // drain the last pending y tile
        __syncthreads();
        if (ptile >= 0 && tid < TILE_E) {
            const float* r = s_red[cur ^ 1];
            y[ptile * TILE_E + tid] = r[tid] + r[32 + tid] + r[64 + tid]
                                    + r[96 + tid] + b2v;
        }
    }
}

extern "C" void kernel_launch(void* const* d_in, const int* in_sizes, int n_in,
                              void* d_out, int out_size, void* d_ws, size_t ws_size,
                              hipStream_t stream) {
    const float* nodes = (const float*)d_in[0];
    const int*   eidx  = (const int*)d_in[1];
    const float* W1    = (const float*)d_in[2];
    // d_in[3] = b1 : analytically cancelled by batch-norm, unused
    const float* gamma = (const float*)d_in[4];
    const float* beta  = (const float*)d_in[5];
    const float* W2    = (const float*)d_in[6];
    const float* b2    = (const float*)d_in[7];

    float* ws    = (float*)d_ws;
    float* gstat = ws;          // 512 f32: sum_h[256], sumsq_h[256]
    unsigned* nbf = (unsigned*)((char*)d_ws + 4096);   // 128 MB bf16 node table
    float* y     = (float*)d_out;

    const size_t T_BYTES = (size_t)N_NODES * IN_DIM_K * 2;   // 128 MB
    const bool fast = ws_size >= (4096 + T_BYTES);

    if (fast) {
        convert_nodes_kernel<<<CONV_GRID, 256, 0, stream>>>(nodes, nbf, gstat);
        hadamard_mlp_kernel<true, true><<<MAIN_GRID, 256, 0, stream>>>(
            nodes, nbf, eidx, W1, W2, b2, gstat, gamma, beta, y);
        hadamard_mlp_kernel<false, true><<<MAIN_GRID, 256, 0, stream>>>(
            nodes, nbf, eidx, W1, W2, b2, gstat, gamma, beta, y);
    } else {
        zero_stats_kernel<<<1, 512, 0, stream>>>(gstat);
        hadamard_mlp_kernel<true, false><<<MAIN_GRID, 256, 0, stream>>>(
            nodes, nbf, eidx, W1, W2, b2, gstat, gamma, beta, y);
        hadamard_mlp_kernel<false, false><<<MAIN_GRID, 256, 0, stream>>>(
            nodes, nbf, eidx, W1, W2, b2, gstat, gamma, beta, y);
    }
}